// Round 16
// baseline (185.242 us; speedup 1.0000x reference)
//
#include <hip/hip_runtime.h>
#include <hip/hip_bf16.h>

#define BB 4
#define CC 256
#define CI 128
#define NPIX 9216      // 96*96
#define MPIX 2304      // 48*48
#define WIMG 96
#define WPOOL 48
#define NSPLIT 2
#define KTPS 18        // KV tiles per split (36/NSPLIT)

typedef _Float16 f16x2 __attribute__((ext_vector_type(2)));
typedef _Float16 f16x4 __attribute__((ext_vector_type(4)));
typedef _Float16 f16x8 __attribute__((ext_vector_type(8)));
typedef float f32x4 __attribute__((ext_vector_type(4)));

// async global->LDS, 16B per lane, LDS dest = wave-uniform base + lane*16
static __device__ __forceinline__ void gload16(const void* g, void* lds) {
  __builtin_amdgcn_global_load_lds(
      (const __attribute__((address_space(1))) unsigned int*)g,
      (__attribute__((address_space(3))) unsigned int*)lds, 16, 0, 0);
}

// ---------------- K0: weights fp32 -> fp16 ---------------------------------
__global__ __launch_bounds__(256) void k_prep(
    const float* __restrict__ Wt, const float* __restrict__ Wg,
    const float* __restrict__ Wp, const float* __restrict__ Ww,
    _Float16* __restrict__ Wall, _Float16* __restrict__ Wwh)
{
  int i = blockIdx.x * 256 + threadIdx.x;
  if (i < 98304) {
    int o = i >> 8, c = i & 255;
    float v = (o < 128) ? Wt[o * 256 + c]
            : (o < 256) ? Wg[(o - 128) * 256 + c]
                        : Wp[(o - 256) * 256 + c];
    Wall[i] = (_Float16)v;
  } else {
    int j = i - 98304;
    Wwh[j] = (_Float16)Ww[j];
  }
}

// ---------------- K0b: x transpose -> xt[b][p][c] fp16 ---------------------
__global__ __launch_bounds__(256) void k_xt(
    const float* __restrict__ x, _Float16* __restrict__ xt)
{
  const int nt = blockIdx.x, ct = blockIdx.y, b = blockIdx.z;
  const int n0 = nt * 64, c0 = ct * 64;
  __shared__ float L[64][65];
  const int t = threadIdx.x;
  #pragma unroll
  for (int i = 0; i < 16; ++i) {
    int idx = i * 256 + t, c = idx >> 6, n = idx & 63;
    L[c][n] = x[(size_t)(b * CC + c0 + c) * NPIX + n0 + n];
  }
  __syncthreads();
  #pragma unroll
  for (int i = 0; i < 4; ++i) {
    int idx = i * 256 + t, n = idx >> 4, cg = idx & 15;
    f16x4 v;
    v[0] = (_Float16)L[cg * 4 + 0][n]; v[1] = (_Float16)L[cg * 4 + 1][n];
    v[2] = (_Float16)L[cg * 4 + 2][n]; v[3] = (_Float16)L[cg * 4 + 3][n];
    *(f16x4*)&xt[(size_t)(b * NPIX + n0 + n) * 256 + c0 + cg * 4] = v;
  }
}

// ---------------- K1: theta/g/phi convs, fp16 MFMA -------------------------
__global__ __launch_bounds__(256) void k_convA(
    const _Float16* __restrict__ xt, const _Float16* __restrict__ Wall,
    const float* __restrict__ bt, const float* __restrict__ bg,
    const float* __restrict__ bp,
    _Float16* __restrict__ th_h, _Float16* __restrict__ gphi)
{
  const int pt = blockIdx.x, ot = blockIdx.y, b = blockIdx.z;
  const int p0 = pt * 128, o0 = ot * 128;
  __shared__ char smem[34816];
  char* WsB = smem;
  char* XsB = smem + 8192;
  const int tid = threadIdx.x;
  const int l = tid & 63, w = tid >> 6;
  const int l15 = l & 15, g16 = l >> 4;
  const int wo = (w & 1) * 64, wp = (w >> 1) * 64;

  f32x4 acc[4][4] = {};
  for (int k0 = 0; k0 < 256; k0 += 32) {
    #pragma unroll
    for (int i = 0; i < 2; ++i) {
      int idx = i * 256 + tid, r = idx >> 2, cg = idx & 3;
      int sw = (cg ^ ((r >> 1) & 3)) * 16;
      *(int4*)(WsB + r * 64 + sw) =
          *(const int4*)&Wall[(size_t)(o0 + r) * 256 + k0 + cg * 8];
      *(int4*)(XsB + r * 64 + sw) =
          *(const int4*)&xt[(size_t)(b * NPIX + p0 + r) * 256 + k0 + cg * 8];
    }
    __syncthreads();
    f16x8 af[4], bf[4];
    #pragma unroll
    for (int f = 0; f < 4; ++f) {
      int ro = wo + f * 16 + l15;
      af[f] = *(const f16x8*)(WsB + ro * 64 + ((g16 ^ ((ro >> 1) & 3)) * 16));
      int rp = wp + f * 16 + l15;
      bf[f] = *(const f16x8*)(XsB + rp * 64 + ((g16 ^ ((rp >> 1) & 3)) * 16));
    }
    #pragma unroll
    for (int of = 0; of < 4; ++of)
      #pragma unroll
      for (int pf = 0; pf < 4; ++pf)
        acc[of][pf] = __builtin_amdgcn_mfma_f32_16x16x32_f16(af[of], bf[pf], acc[of][pf], 0, 0, 0);
    __syncthreads();
  }

  if (o0 == 0) {
    _Float16* T = (_Float16*)smem;   // [128][136]
    #pragma unroll
    for (int of = 0; of < 4; ++of) {
      const float4 bb = *(const float4*)&bt[wo + of * 16 + g16 * 4];
      float bv[4] = {bb.x, bb.y, bb.z, bb.w};
      #pragma unroll
      for (int pf = 0; pf < 4; ++pf) {
        f16x4 v;
        #pragma unroll
        for (int r = 0; r < 4; ++r) v[r] = (_Float16)(acc[of][pf][r] + bv[r]);
        *(f16x4*)&T[(wp + pf * 16 + l15) * 136 + wo + of * 16 + g16 * 4] = v;
      }
    }
    __syncthreads();
    #pragma unroll
    for (int i = 0; i < 8; ++i) {
      int idx = i * 256 + tid, row = idx >> 4, cg = idx & 15;
      *(int4*)&th_h[(size_t)(b * NPIX + p0 + row) * 128 + cg * 8] =
          *(const int4*)&T[row * 136 + cg * 8];
    }
  } else {
    const float* bsel = (o0 == 128) ? bg : bp;
    const int chbase = o0 - 128;
    #pragma unroll
    for (int of = 0; of < 4; ++of) {
      const float4 bb = *(const float4*)&bsel[wo + of * 16 + g16 * 4];
      float bv[4] = {bb.x, bb.y, bb.z, bb.w};
      #pragma unroll
      for (int pf = 0; pf < 4; ++pf)
        #pragma unroll
        for (int r = 0; r < 4; ++r) {
          int ch = chbase + wo + of * 16 + g16 * 4 + r;
          gphi[(size_t)(b * 256 + ch) * NPIX + p0 + wp + pf * 16 + l15] =
              (_Float16)(acc[of][pf][r] + bv[r]);
        }
    }
  }
}

// ---------------- K2: 2x2 maxpool fp16 -> g_h[c][m], phi_h[m][c] -----------
__global__ __launch_bounds__(256) void k_pool2(
    const _Float16* __restrict__ gphi,
    _Float16* __restrict__ g_h, _Float16* __restrict__ phi_h)
{
  const int mt = blockIdx.x, ct = blockIdx.y, b = blockIdx.z;
  const int m0 = mt * 64, c0 = ct * 32;
  __shared__ _Float16 Lg[32][72], Lp[32][72];
  const int t = threadIdx.x;
  #pragma unroll
  for (int i = 0; i < 8; ++i) {
    int idx = i * 256 + t, c = idx >> 6, m = idx & 63;
    int mm = m0 + m, hp = mm / WPOOL, wp = mm % WPOOL;
    const _Float16* sg = &gphi[(size_t)(b * 256 + c0 + c) * NPIX + hp * 192 + wp * 2];
    f16x2 a0 = *(const f16x2*)sg;
    f16x2 a1 = *(const f16x2*)(sg + WIMG);
    Lg[c][m] = (_Float16)fmaxf(fmaxf((float)a0[0], (float)a0[1]),
                               fmaxf((float)a1[0], (float)a1[1]));
    const _Float16* sp = sg + (size_t)128 * NPIX;
    f16x2 b0 = *(const f16x2*)sp;
    f16x2 b1 = *(const f16x2*)(sp + WIMG);
    Lp[c][m] = (_Float16)fmaxf(fmaxf((float)b0[0], (float)b0[1]),
                               fmaxf((float)b1[0], (float)b1[1]));
  }
  __syncthreads();
  {
    int c = t >> 3, mq = t & 7;
    f16x8 v = *(const f16x8*)&Lg[c][mq * 8];
    *(f16x8*)&g_h[(size_t)(b * CI + c0 + c) * MPIX + m0 + mq * 8] = v;
  }
  #pragma unroll
  for (int i = 0; i < 2; ++i) {
    int idx = i * 256 + t, m = idx >> 3, cg = idx & 7;
    f16x4 v;
    v[0] = Lp[cg * 4 + 0][m]; v[1] = Lp[cg * 4 + 1][m];
    v[2] = Lp[cg * 4 + 2][m]; v[3] = Lp[cg * 4 + 3][m];
    *(f16x4*)&phi_h[(size_t)(b * MPIX + m0 + m) * 128 + c0 + cg * 4] = v;
  }
}

// ---------------- K3: flash attention, fp16 MFMA, SPLIT-KV x2 ---------------
// r10/r14 schedule with one structural change: P is kept in REGISTERS across
// barrier #1 and then written into the CURRENT phi buffer (dead after the
// barrier: all QK reads done; its next overwrite is one full iteration away).
// LDS = Ph0+Ph1+Gl = 48 KiB -> 3 blocks/CU -> all 576 blocks co-resident in
// ONE residency wave (the 2-blocks/CU layouts paid a 2x makespan tail).
__global__ __launch_bounds__(256, 3) void k_attn(
    const _Float16* __restrict__ th_h,
    const _Float16* __restrict__ phi_h,
    const _Float16* __restrict__ g_h,
    _Float16* __restrict__ y_part,
    float2* __restrict__ ml)
{
  const int qt = blockIdx.x, b = blockIdx.y, split = blockIdx.z;
  const int n0 = qt * 128;
  const int kt0 = split * KTPS;
  __shared__ char smem[49152];
  // [0,16K): Ph0  [16K,32K): Ph1  [32K,48K): Gl
  // P (wave-private 4K) aliases the current (dead-after-barrier-1) Ph buffer.
  char* const GlB = smem + 32768;

  const int tid = threadIdx.x;
  const int l = tid & 63, wid = tid >> 6;
  const int l15 = l & 15, g16 = l >> 4;
  const int wq0 = wid * 32;

  f16x8 thf[2][4];
  #pragma unroll
  for (int qh = 0; qh < 2; ++qh) {
    const size_t row = (size_t)(b * NPIX + n0 + wq0 + 16 * qh + l15) * 128;
    #pragma unroll
    for (int cs = 0; cs < 4; ++cs)
      thf[qh][cs] = *(const f16x8*)&th_h[row + 32 * cs + 8 * g16];
  }

  auto stage_phi = [&](int bufsel, int kt) {
    char* dst = smem + bufsel * 16384;
    const int m1 = kt * 64;
    #pragma unroll
    for (int j = 0; j < 4; ++j) {
      int mbase = wid * 16 + j * 4;
      int m = mbase + (l >> 4);
      int cg = (l & 15) ^ (m & 7);
      gload16(&phi_h[((size_t)(b * MPIX + m1 + m) << 7) + cg * 8],
              dst + mbase * 256);
    }
  };
  auto stage_g = [&](int kt) {
    const int m1 = kt * 64;
    #pragma unroll
    for (int j = 0; j < 4; ++j) {
      int cbase = wid * 32 + j * 8;
      int c = cbase + (l >> 3);
      int cg = (l & 7) ^ (c & 7);
      gload16(&g_h[(size_t)(b * CI + c) * MPIX + m1 + cg * 8],
              GlB + cbase * 128);
    }
  };

  stage_phi(0, kt0);
  __syncthreads();

  f32x4 yacc[2][8] = {};
  float mrun[2] = {-1e30f, -1e30f};
  float lrun[2] = {0.f, 0.f};

  #pragma unroll 1
  for (int kt = kt0; kt < kt0 + KTPS; ++kt) {
    stage_g(kt);   // async; drained at barrier #1, overlaps QK + softmax
    char* const phC = smem + ((kt - kt0) & 1) * 16384;

    // ---- scores: S^T[m][q] ----
    f32x4 sacc[4][2] = {};
    #pragma unroll
    for (int cs = 0; cs < 4; ++cs) {
      const int cb = cs * 64 + g16 * 16;
      #pragma unroll
      for (int mf = 0; mf < 4; ++mf) {
        const int m = 16 * mf + l15;
        f16x8 aph = *(const f16x8*)(phC + m * 256 + (cb ^ ((m & 7) << 4)));
        sacc[mf][0] = __builtin_amdgcn_mfma_f32_16x16x32_f16(aph, thf[0][cs], sacc[mf][0], 0, 0, 0);
        sacc[mf][1] = __builtin_amdgcn_mfma_f32_16x16x32_f16(aph, thf[1][cs], sacc[mf][1], 0, 0, 0);
      }
    }

    // ---- online softmax (lane owns q = wq0 + 16*qh + l15); P stays in regs
    float scl2[2];
    f16x4 pr[4][2];
    #pragma unroll
    for (int qh = 0; qh < 2; ++qh) {
      float mx = -1e30f;
      #pragma unroll
      for (int mf = 0; mf < 4; ++mf)
        #pragma unroll
        for (int r = 0; r < 4; ++r) mx = fmaxf(mx, sacc[mf][qh][r]);
      mx = fmaxf(mx, __shfl_xor(mx, 16, 64));
      mx = fmaxf(mx, __shfl_xor(mx, 32, 64));
      const float mo = mrun[qh];
      const float mn = fmaxf(mo, mx);
      float sum = 0.f;
      #pragma unroll
      for (int mf = 0; mf < 4; ++mf)
        #pragma unroll
        for (int r = 0; r < 4; ++r) {
          float p = __expf(sacc[mf][qh][r] - mn);
          _Float16 ph = (_Float16)p;
          pr[mf][qh][r] = ph;
          sum += (float)ph;
        }
      sum += __shfl_xor(sum, 16, 64);
      sum += __shfl_xor(sum, 32, 64);
      const float sc = __expf(mo - mn);
      scl2[qh] = sc;
      lrun[qh] = lrun[qh] * sc + sum;
      mrun[qh] = mn;
    }

    // ---- rescale yacc ----
    {
      float rs[2][4];
      #pragma unroll
      for (int r = 0; r < 4; ++r) {
        rs[0][r] = __shfl(scl2[0], 4 * g16 + r, 64);
        rs[1][r] = __shfl(scl2[1], 4 * g16 + r, 64);
      }
      #pragma unroll
      for (int qi = 0; qi < 2; ++qi)
        #pragma unroll
        for (int cf = 0; cf < 8; ++cf)
          #pragma unroll
          for (int r = 0; r < 4; ++r)
            yacc[qi][cf][r] *= rs[qi][r];
    }

    __syncthreads();   // #1: g tile arrived; all QK reads of phC done (phC now dead)

    // ---- P -> wave-private slice of the dead phC buffer (fp16, swizzled) ----
    char* const PlB = phC + (wid << 12);
    #pragma unroll
    for (int qh = 0; qh < 2; ++qh) {
      const int qw = l15 + 16 * qh;
      char* prow = PlB + qw * 128;
      #pragma unroll
      for (int mf = 0; mf < 4; ++mf)
        *(f16x4*)(prow + ((32 * mf + 8 * g16) ^ ((qw & 7) << 4))) = pr[mf][qh];
    }

    if (kt + 1 < kt0 + KTPS)
      stage_phi((kt + 1 - kt0) & 1, kt + 1);   // async into the OTHER buffer

    // ---- PV: y[q][c] += P[q][m] * g[m][c] ----
    #pragma unroll
    for (int ms = 0; ms < 2; ++ms) {
      const int mb = ms * 64 + g16 * 16;
      const int q0w = l15, q1w = l15 + 16;
      f16x8 pa0 = *(const f16x8*)(PlB + q0w * 128 + (mb ^ ((q0w & 7) << 4)));
      f16x8 pa1 = *(const f16x8*)(PlB + q1w * 128 + (mb ^ ((q1w & 7) << 4)));
      #pragma unroll
      for (int cf = 0; cf < 8; ++cf) {
        const int c = 16 * cf + l15;
        f16x8 gb = *(const f16x8*)(GlB + c * 128 + (mb ^ ((c & 7) << 4)));
        yacc[0][cf] = __builtin_amdgcn_mfma_f32_16x16x32_f16(pa0, gb, yacc[0][cf], 0, 0, 0);
        yacc[1][cf] = __builtin_amdgcn_mfma_f32_16x16x32_f16(pa1, gb, yacc[1][cf], 0, 0, 0);
      }
    }

    __syncthreads();   // #2: next phi arrived; Gl free for next stage_g
  }

  // ---- epilogue: per-q (m,l); UNNORMALIZED y via LDS transpose ----
  if (g16 == 0) {
    #pragma unroll
    for (int qh = 0; qh < 2; ++qh)
      ml[(size_t)(split * BB + b) * NPIX + n0 + wq0 + 16 * qh + l15] =
          make_float2(mrun[qh], lrun[qh]);
  }
  _Float16* Yl = (_Float16*)smem;   // [128][136] = 34816 B < 48K
  #pragma unroll
  for (int qi = 0; qi < 2; ++qi)
    #pragma unroll
    for (int cf = 0; cf < 8; ++cf)
      #pragma unroll
      for (int r = 0; r < 4; ++r)
        Yl[(wq0 + 16 * qi + 4 * g16 + r) * 136 + 16 * cf + l15] =
            (_Float16)yacc[qi][cf][r];
  __syncthreads();
  #pragma unroll
  for (int i = 0; i < 8; ++i) {
    int idx = i * 256 + tid, row = idx >> 4, cg = idx & 15;
    *(int4*)&y_part[(size_t)((split * BB + b) * NPIX + n0 + row) * 128 + cg * 8] =
        *(const int4*)&Yl[row * 136 + cg * 8];
  }
}

// ---------------- K3b: merge the two KV splits -----------------------------
__global__ __launch_bounds__(256) void k_comb(
    const _Float16* __restrict__ y_part, const float2* __restrict__ ml,
    _Float16* __restrict__ y_h)
{
  int idx = blockIdx.x * 256 + threadIdx.x;   // BB*NPIX*16 threads
  int cg = idx & 15;
  int n  = (idx >> 4) % NPIX;
  int b  = (idx >> 4) / NPIX;
  float2 a0 = ml[(size_t)b * NPIX + n];
  float2 a1 = ml[(size_t)(BB + b) * NPIX + n];
  float M = fmaxf(a0.x, a1.x);
  float w0 = __expf(a0.x - M), w1 = __expf(a1.x - M);
  float inv = 1.0f / (w0 * a0.y + w1 * a1.y);
  w0 *= inv; w1 *= inv;
  f16x8 v0 = *(const f16x8*)&y_part[(size_t)(b * NPIX + n) * 128 + cg * 8];
  f16x8 v1 = *(const f16x8*)&y_part[(size_t)((BB + b) * NPIX + n) * 128 + cg * 8];
  f16x8 o;
  #pragma unroll
  for (int r = 0; r < 8; ++r)
    o[r] = (_Float16)(w0 * (float)v0[r] + w1 * (float)v1[r]);
  *(f16x8*)&y_h[(size_t)(b * NPIX + n) * 128 + cg * 8] = o;
}

// ---------------- K4: W-conv fp16 MFMA: z[b][o][n] fp16 --------------------
__global__ __launch_bounds__(256) void k_wconv(
    const _Float16* __restrict__ y_h, const _Float16* __restrict__ Wwh,
    const float* __restrict__ bw, _Float16* __restrict__ z_h)
{
  const int nt = blockIdx.x, ot = blockIdx.y, b = blockIdx.z;
  const int n0 = nt * 128, o0 = ot * 128;
  __shared__ char smem[16384];
  char* WsB = smem;
  char* YsB = smem + 8192;
  const int tid = threadIdx.x;
  const int l = tid & 63, w = tid >> 6;
  const int l15 = l & 15, g16 = l >> 4;
  const int wo = (w & 1) * 64, wn = (w >> 1) * 64;

  f32x4 acc[4][4] = {};
  for (int k0 = 0; k0 < 128; k0 += 32) {
    #pragma unroll
    for (int i = 0; i < 2; ++i) {
      int idx = i * 256 + tid, r = idx >> 2, cg = idx & 3;
      int sw = (cg ^ ((r >> 1) & 3)) * 16;
      *(int4*)(WsB + r * 64 + sw) =
          *(const int4*)&Wwh[(size_t)(o0 + r) * 128 + k0 + cg * 8];
      *(int4*)(YsB + r * 64 + sw) =
          *(const int4*)&y_h[(size_t)(b * NPIX + n0 + r) * 128 + k0 + cg * 8];
    }
    __syncthreads();
    f16x8 af[4], bf[4];
    #pragma unroll
    for (int f = 0; f < 4; ++f) {
      int ro = wo + f * 16 + l15;
      af[f] = *(const f16x8*)(WsB + ro * 64 + ((g16 ^ ((ro >> 1) & 3)) * 16));
      int rn = wn + f * 16 + l15;
      bf[f] = *(const f16x8*)(YsB + rn * 64 + ((g16 ^ ((rn >> 1) & 3)) * 16));
    }
    #pragma unroll
    for (int of = 0; of < 4; ++of)
      #pragma unroll
      for (int pf = 0; pf < 4; ++pf)
        acc[of][pf] = __builtin_amdgcn_mfma_f32_16x16x32_f16(af[of], bf[pf], acc[of][pf], 0, 0, 0);
    __syncthreads();
  }
  #pragma unroll
  for (int of = 0; of < 4; ++of) {
    const float4 bb = *(const float4*)&bw[o0 + wo + of * 16 + g16 * 4];
    float bv[4] = {bb.x, bb.y, bb.z, bb.w};
    #pragma unroll
    for (int pf = 0; pf < 4; ++pf)
      #pragma unroll
      for (int r = 0; r < 4; ++r)
        z_h[(size_t)(b * CC + o0 + wo + of * 16 + g16 * 4 + r) * NPIX +
            n0 + wn + pf * 16 + l15] = (_Float16)(acc[of][pf][r] + bv[r]);
  }
}

// ---------------- K4b: per-channel batch stats (z fp16) ---------------------
__global__ __launch_bounds__(256) void k_stats(
    const _Float16* __restrict__ z_h, float* __restrict__ stats)
{
  const int o = blockIdx.x, t = threadIdx.x;
  float s = 0.f, s2 = 0.f;
  for (int b = 0; b < BB; ++b) {
    const _Float16* z = &z_h[(size_t)(b * CC + o) * NPIX];
    for (int i = t; i < NPIX / 8; i += 256) {
      f16x8 v = *(const f16x8*)&z[i * 8];
      #pragma unroll
      for (int r = 0; r < 8; ++r) {
        float f = (float)v[r];
        s += f; s2 += f * f;
      }
    }
  }
  #pragma unroll
  for (int off = 1; off < 64; off <<= 1) {
    s  += __shfl_xor(s,  off, 64);
    s2 += __shfl_xor(s2, off, 64);
  }
  __shared__ float ls[4], ls2[4];
  if ((t & 63) == 0) { ls[t >> 6] = s; ls2[t >> 6] = s2; }
  __syncthreads();
  if (t == 0) {
    float S  = ls[0] + ls[1] + ls[2] + ls[3];
    float S2 = ls2[0] + ls2[1] + ls2[2] + ls2[3];
    const float invn = 1.0f / (float)(BB * NPIX);
    float mean = S * invn;
    float var  = S2 * invn - mean * mean;
    stats[o] = mean;
    stats[CC + o] = rsqrtf(var + 1e-5f);
  }
}

// ---------------- K5: BN apply + residual (z fp16, 8 elems/thread) ----------
__global__ __launch_bounds__(256) void k_out(
    const _Float16* __restrict__ z_h, const float* __restrict__ x,
    const float* __restrict__ gamma, const float* __restrict__ beta,
    const float* __restrict__ stats, float* __restrict__ out)
{
  int idx = blockIdx.x * 256 + threadIdx.x;
  const int total8 = BB * CC * NPIX / 8;
  if (idx >= total8) return;
  size_t e = (size_t)idx * 8;
  int p = (int)(e % NPIX);
  int o = (int)((e / NPIX) % CC);
  int b = (int)(e / ((size_t)CC * NPIX));
  float a  = stats[CC + o] * gamma[o];
  float c0 = beta[o] - stats[o] * a;
  f16x8 z = *(const f16x8*)&z_h[(size_t)(b * CC + o) * NPIX + p];
  float4 x0 = *(const float4*)&x[e];
  float4 x1 = *(const float4*)&x[e + 4];
  float4 r0, r1;
  r0.x = (float)z[0] * a + c0 + x0.x;
  r0.y = (float)z[1] * a + c0 + x0.y;
  r0.z = (float)z[2] * a + c0 + x0.z;
  r0.w = (float)z[3] * a + c0 + x0.w;
  r1.x = (float)z[4] * a + c0 + x1.x;
  r1.y = (float)z[5] * a + c0 + x1.y;
  r1.z = (float)z[6] * a + c0 + x1.z;
  r1.w = (float)z[7] * a + c0 + x1.w;
  *(float4*)&out[e] = r0;
  *(float4*)&out[e + 4] = r1;
}

extern "C" void kernel_launch(void* const* d_in, const int* in_sizes, int n_in,
                              void* d_out, int out_size, void* d_ws, size_t ws_size,
                              hipStream_t stream)
{
  const float* x     = (const float*)d_in[0];
  const float* Wg    = (const float*)d_in[1];
  const float* bg    = (const float*)d_in[2];
  const float* Wt    = (const float*)d_in[3];
  const float* bt    = (const float*)d_in[4];
  const float* Wp    = (const float*)d_in[5];
  const float* bp    = (const float*)d_in[6];
  const float* Ww    = (const float*)d_in[7];
  const float* bw    = (const float*)d_in[8];
  const float* gamma = (const float*)d_in[9];
  const float* beta  = (const float*)d_in[10];
  float* out = (float*)d_out;

  // workspace (lifetime-aliased):
  //  region A [0, 37.75MB): xt f16 -> y_part f16 [2][4][9216][128] -> z_h f16
  //  region B [37.75, 56.6MB): gphi f16 -> y_h f16
  //  region C [56.6MB ...): th_h, g_h, phi_h, Wall, Wwh, stats, ml
  char* wsb = (char*)d_ws;
  _Float16* xt     = (_Float16*)wsb;
  _Float16* y_part = (_Float16*)wsb;
  _Float16* z_h    = (_Float16*)wsb;
  char* p2 = wsb + 37748736;
  _Float16* gphi  = (_Float16*)p2;
  _Float16* y_h   = (_Float16*)p2;
  char* p3 = p2 + 18874368;
  _Float16* th_h  = (_Float16*)p3;
  _Float16* g_h   = (_Float16*)(p3 + 9437184);
  _Float16* phi_h = (_Float16*)(p3 + 11796480);
  _Float16* Wall  = (_Float16*)(p3 + 14155776);
  _Float16* Wwh   = (_Float16*)(p3 + 14352384);
  float*    stats = (float*)(p3 + 14417920);            // [2][256]
  float2*   ml    = (float2*)(p3 + 14420992);           // [2][4][9216]

  k_prep<<<512, 256, 0, stream>>>(Wt, Wg, Wp, Ww, Wall, Wwh);

  dim3 gxt(NPIX / 64, CC / 64, BB);
  k_xt<<<gxt, 256, 0, stream>>>(x, xt);

  dim3 g1(NPIX / 128, 3, BB);
  k_convA<<<g1, 256, 0, stream>>>(xt, Wall, bt, bg, bp, th_h, gphi);

  dim3 g2(MPIX / 64, 4, BB);
  k_pool2<<<g2, 256, 0, stream>>>(gphi, g_h, phi_h);

  dim3 g3(NPIX / 128, BB, NSPLIT);
  k_attn<<<g3, 256, 0, stream>>>(th_h, phi_h, g_h, y_part, ml);

  k_comb<<<(BB * NPIX * 16) / 256, 256, 0, stream>>>(y_part, ml, y_h);

  dim3 g4(NPIX / 128, CC / 128, BB);
  k_wconv<<<g4, 256, 0, stream>>>(y_h, Wwh, bw, z_h);

  k_stats<<<CC, 256, 0, stream>>>(z_h, stats);

  k_out<<<(BB * CC * NPIX / 8 + 255) / 256, 256, 0, stream>>>(z_h, x, gamma, beta, stats, out);
}

// Round 17
// 150.691 us; speedup vs baseline: 1.2293x; 1.2293x over previous
//
#include <hip/hip_runtime.h>
#include <hip/hip_bf16.h>

#define BB 4
#define CC 256
#define CI 128
#define NPIX 9216      // 96*96
#define MPIX 2304      // 48*48
#define WIMG 96
#define WPOOL 48
#define NSPLIT 3
#define KTPS 12        // KV tiles per split (36/NSPLIT)

typedef _Float16 f16x2 __attribute__((ext_vector_type(2)));
typedef _Float16 f16x4 __attribute__((ext_vector_type(4)));
typedef _Float16 f16x8 __attribute__((ext_vector_type(8)));
typedef float f32x4 __attribute__((ext_vector_type(4)));

// async global->LDS, 16B per lane, LDS dest = wave-uniform base + lane*16
static __device__ __forceinline__ void gload16(const void* g, void* lds) {
  __builtin_amdgcn_global_load_lds(
      (const __attribute__((address_space(1))) unsigned int*)g,
      (__attribute__((address_space(3))) unsigned int*)lds, 16, 0, 0);
}

// ---------------- K0: weights fp32 -> fp16 ---------------------------------
__global__ __launch_bounds__(256) void k_prep(
    const float* __restrict__ Wt, const float* __restrict__ Wg,
    const float* __restrict__ Wp, const float* __restrict__ Ww,
    _Float16* __restrict__ Wall, _Float16* __restrict__ Wwh)
{
  int i = blockIdx.x * 256 + threadIdx.x;
  if (i < 98304) {
    int o = i >> 8, c = i & 255;
    float v = (o < 128) ? Wt[o * 256 + c]
            : (o < 256) ? Wg[(o - 128) * 256 + c]
                        : Wp[(o - 256) * 256 + c];
    Wall[i] = (_Float16)v;
  } else {
    int j = i - 98304;
    Wwh[j] = (_Float16)Ww[j];
  }
}

// ---------------- K0b: x transpose -> xt[b][p][c] fp16 ---------------------
__global__ __launch_bounds__(256) void k_xt(
    const float* __restrict__ x, _Float16* __restrict__ xt)
{
  const int nt = blockIdx.x, ct = blockIdx.y, b = blockIdx.z;
  const int n0 = nt * 64, c0 = ct * 64;
  __shared__ float L[64][65];
  const int t = threadIdx.x;
  #pragma unroll
  for (int i = 0; i < 16; ++i) {
    int idx = i * 256 + t, c = idx >> 6, n = idx & 63;
    L[c][n] = x[(size_t)(b * CC + c0 + c) * NPIX + n0 + n];
  }
  __syncthreads();
  #pragma unroll
  for (int i = 0; i < 4; ++i) {
    int idx = i * 256 + t, n = idx >> 4, cg = idx & 15;
    f16x4 v;
    v[0] = (_Float16)L[cg * 4 + 0][n]; v[1] = (_Float16)L[cg * 4 + 1][n];
    v[2] = (_Float16)L[cg * 4 + 2][n]; v[3] = (_Float16)L[cg * 4 + 3][n];
    *(f16x4*)&xt[(size_t)(b * NPIX + n0 + n) * 256 + c0 + cg * 4] = v;
  }
}

// ---------------- K1: theta/g/phi convs, fp16 MFMA -------------------------
__global__ __launch_bounds__(256) void k_convA(
    const _Float16* __restrict__ xt, const _Float16* __restrict__ Wall,
    const float* __restrict__ bt, const float* __restrict__ bg,
    const float* __restrict__ bp,
    _Float16* __restrict__ th_h, _Float16* __restrict__ gphi)
{
  const int pt = blockIdx.x, ot = blockIdx.y, b = blockIdx.z;
  const int p0 = pt * 128, o0 = ot * 128;
  __shared__ char smem[34816];
  char* WsB = smem;
  char* XsB = smem + 8192;
  const int tid = threadIdx.x;
  const int l = tid & 63, w = tid >> 6;
  const int l15 = l & 15, g16 = l >> 4;
  const int wo = (w & 1) * 64, wp = (w >> 1) * 64;

  f32x4 acc[4][4] = {};
  for (int k0 = 0; k0 < 256; k0 += 32) {
    #pragma unroll
    for (int i = 0; i < 2; ++i) {
      int idx = i * 256 + tid, r = idx >> 2, cg = idx & 3;
      int sw = (cg ^ ((r >> 1) & 3)) * 16;
      *(int4*)(WsB + r * 64 + sw) =
          *(const int4*)&Wall[(size_t)(o0 + r) * 256 + k0 + cg * 8];
      *(int4*)(XsB + r * 64 + sw) =
          *(const int4*)&xt[(size_t)(b * NPIX + p0 + r) * 256 + k0 + cg * 8];
    }
    __syncthreads();
    f16x8 af[4], bf[4];
    #pragma unroll
    for (int f = 0; f < 4; ++f) {
      int ro = wo + f * 16 + l15;
      af[f] = *(const f16x8*)(WsB + ro * 64 + ((g16 ^ ((ro >> 1) & 3)) * 16));
      int rp = wp + f * 16 + l15;
      bf[f] = *(const f16x8*)(XsB + rp * 64 + ((g16 ^ ((rp >> 1) & 3)) * 16));
    }
    #pragma unroll
    for (int of = 0; of < 4; ++of)
      #pragma unroll
      for (int pf = 0; pf < 4; ++pf)
        acc[of][pf] = __builtin_amdgcn_mfma_f32_16x16x32_f16(af[of], bf[pf], acc[of][pf], 0, 0, 0);
    __syncthreads();
  }

  if (o0 == 0) {
    _Float16* T = (_Float16*)smem;   // [128][136]
    #pragma unroll
    for (int of = 0; of < 4; ++of) {
      const float4 bb = *(const float4*)&bt[wo + of * 16 + g16 * 4];
      float bv[4] = {bb.x, bb.y, bb.z, bb.w};
      #pragma unroll
      for (int pf = 0; pf < 4; ++pf) {
        f16x4 v;
        #pragma unroll
        for (int r = 0; r < 4; ++r) v[r] = (_Float16)(acc[of][pf][r] + bv[r]);
        *(f16x4*)&T[(wp + pf * 16 + l15) * 136 + wo + of * 16 + g16 * 4] = v;
      }
    }
    __syncthreads();
    #pragma unroll
    for (int i = 0; i < 8; ++i) {
      int idx = i * 256 + tid, row = idx >> 4, cg = idx & 15;
      *(int4*)&th_h[(size_t)(b * NPIX + p0 + row) * 128 + cg * 8] =
          *(const int4*)&T[row * 136 + cg * 8];
    }
  } else {
    const float* bsel = (o0 == 128) ? bg : bp;
    const int chbase = o0 - 128;
    #pragma unroll
    for (int of = 0; of < 4; ++of) {
      const float4 bb = *(const float4*)&bsel[wo + of * 16 + g16 * 4];
      float bv[4] = {bb.x, bb.y, bb.z, bb.w};
      #pragma unroll
      for (int pf = 0; pf < 4; ++pf)
        #pragma unroll
        for (int r = 0; r < 4; ++r) {
          int ch = chbase + wo + of * 16 + g16 * 4 + r;
          gphi[(size_t)(b * 256 + ch) * NPIX + p0 + wp + pf * 16 + l15] =
              (_Float16)(acc[of][pf][r] + bv[r]);
        }
    }
  }
}

// ---------------- K2: 2x2 maxpool fp16 -> g_h[c][m], phi_h[m][c] -----------
__global__ __launch_bounds__(256) void k_pool2(
    const _Float16* __restrict__ gphi,
    _Float16* __restrict__ g_h, _Float16* __restrict__ phi_h)
{
  const int mt = blockIdx.x, ct = blockIdx.y, b = blockIdx.z;
  const int m0 = mt * 64, c0 = ct * 32;
  __shared__ _Float16 Lg[32][72], Lp[32][72];
  const int t = threadIdx.x;
  #pragma unroll
  for (int i = 0; i < 8; ++i) {
    int idx = i * 256 + t, c = idx >> 6, m = idx & 63;
    int mm = m0 + m, hp = mm / WPOOL, wp = mm % WPOOL;
    const _Float16* sg = &gphi[(size_t)(b * 256 + c0 + c) * NPIX + hp * 192 + wp * 2];
    f16x2 a0 = *(const f16x2*)sg;
    f16x2 a1 = *(const f16x2*)(sg + WIMG);
    Lg[c][m] = (_Float16)fmaxf(fmaxf((float)a0[0], (float)a0[1]),
                               fmaxf((float)a1[0], (float)a1[1]));
    const _Float16* sp = sg + (size_t)128 * NPIX;
    f16x2 b0 = *(const f16x2*)sp;
    f16x2 b1 = *(const f16x2*)(sp + WIMG);
    Lp[c][m] = (_Float16)fmaxf(fmaxf((float)b0[0], (float)b0[1]),
                               fmaxf((float)b1[0], (float)b1[1]));
  }
  __syncthreads();
  {
    int c = t >> 3, mq = t & 7;
    f16x8 v = *(const f16x8*)&Lg[c][mq * 8];
    *(f16x8*)&g_h[(size_t)(b * CI + c0 + c) * MPIX + m0 + mq * 8] = v;
  }
  #pragma unroll
  for (int i = 0; i < 2; ++i) {
    int idx = i * 256 + t, m = idx >> 3, cg = idx & 7;
    f16x4 v;
    v[0] = Lp[cg * 4 + 0][m]; v[1] = Lp[cg * 4 + 1][m];
    v[2] = Lp[cg * 4 + 2][m]; v[3] = Lp[cg * 4 + 3][m];
    *(f16x4*)&phi_h[(size_t)(b * MPIX + m0 + m) * 128 + c0 + cg * 4] = v;
  }
}

// ---------------- K3: flash attention, fp16 MFMA, SPLIT-KV x3 ---------------
// EXACT round-15 kernel (best measured: attn 82.8 us, total 159.1).
// Ph double-buffer (2x16K) + Gl (16K) + Pl (16K) = 64 KiB, gload_lds staging,
// launch_bounds(256,2), __expf, no setprio. Do NOT restructure: six variants
// (q64, single-buffer, 48K+bounds3, setprio, exp2, defer-max) all regressed.
__global__ __launch_bounds__(256, 2) void k_attn(
    const _Float16* __restrict__ th_h,
    const _Float16* __restrict__ phi_h,
    const _Float16* __restrict__ g_h,
    _Float16* __restrict__ y_part,
    float2* __restrict__ ml)
{
  const int qt = blockIdx.x, b = blockIdx.y, split = blockIdx.z;
  const int n0 = qt * 128;
  const int kt0 = split * KTPS;
  __shared__ char smem[65536];
  // [0,16K): Ph0  [16K,32K): Ph1  [32K,48K): Gl  [48K,64K): Pl
  char* const GlB = smem + 32768;
  char* const PlB = smem + 49152;

  const int tid = threadIdx.x;
  const int l = tid & 63, wid = tid >> 6;
  const int l15 = l & 15, g16 = l >> 4;
  const int wq0 = wid * 32;

  f16x8 thf[2][4];
  #pragma unroll
  for (int qh = 0; qh < 2; ++qh) {
    const size_t row = (size_t)(b * NPIX + n0 + wq0 + 16 * qh + l15) * 128;
    #pragma unroll
    for (int cs = 0; cs < 4; ++cs)
      thf[qh][cs] = *(const f16x8*)&th_h[row + 32 * cs + 8 * g16];
  }

  auto stage_phi = [&](int bufsel, int kt) {
    char* dst = smem + bufsel * 16384;
    const int m1 = kt * 64;
    #pragma unroll
    for (int j = 0; j < 4; ++j) {
      int mbase = wid * 16 + j * 4;
      int m = mbase + (l >> 4);
      int cg = (l & 15) ^ (m & 7);
      gload16(&phi_h[((size_t)(b * MPIX + m1 + m) << 7) + cg * 8],
              dst + mbase * 256);
    }
  };
  auto stage_g = [&](int kt) {
    const int m1 = kt * 64;
    #pragma unroll
    for (int j = 0; j < 4; ++j) {
      int cbase = wid * 32 + j * 8;
      int c = cbase + (l >> 3);
      int cg = (l & 7) ^ (c & 7);
      gload16(&g_h[(size_t)(b * CI + c) * MPIX + m1 + cg * 8],
              GlB + cbase * 128);
    }
  };

  stage_phi(0, kt0);
  __syncthreads();

  f32x4 yacc[2][8] = {};
  float mrun[2] = {-1e30f, -1e30f};
  float lrun[2] = {0.f, 0.f};

  #pragma unroll 1
  for (int kt = kt0; kt < kt0 + KTPS; ++kt) {
    stage_g(kt);   // async; drained at barrier #1, overlaps QK + softmax
    const char* phC = smem + ((kt - kt0) & 1) * 16384;

    // ---- scores: S^T[m][q] ----
    f32x4 sacc[4][2] = {};
    #pragma unroll
    for (int cs = 0; cs < 4; ++cs) {
      const int cb = cs * 64 + g16 * 16;
      #pragma unroll
      for (int mf = 0; mf < 4; ++mf) {
        const int m = 16 * mf + l15;
        f16x8 aph = *(const f16x8*)(phC + m * 256 + (cb ^ ((m & 7) << 4)));
        sacc[mf][0] = __builtin_amdgcn_mfma_f32_16x16x32_f16(aph, thf[0][cs], sacc[mf][0], 0, 0, 0);
        sacc[mf][1] = __builtin_amdgcn_mfma_f32_16x16x32_f16(aph, thf[1][cs], sacc[mf][1], 0, 0, 0);
      }
    }

    // ---- online softmax (lane owns q = wq0 + 16*qh + l15) ----
    float scl2[2];
    f16x4 pr[4][2];
    #pragma unroll
    for (int qh = 0; qh < 2; ++qh) {
      float mx = -1e30f;
      #pragma unroll
      for (int mf = 0; mf < 4; ++mf)
        #pragma unroll
        for (int r = 0; r < 4; ++r) mx = fmaxf(mx, sacc[mf][qh][r]);
      mx = fmaxf(mx, __shfl_xor(mx, 16, 64));
      mx = fmaxf(mx, __shfl_xor(mx, 32, 64));
      const float mo = mrun[qh];
      const float mn = fmaxf(mo, mx);
      float sum = 0.f;
      #pragma unroll
      for (int mf = 0; mf < 4; ++mf)
        #pragma unroll
        for (int r = 0; r < 4; ++r) {
          float p = __expf(sacc[mf][qh][r] - mn);
          _Float16 ph = (_Float16)p;
          pr[mf][qh][r] = ph;
          sum += (float)ph;
        }
      sum += __shfl_xor(sum, 16, 64);
      sum += __shfl_xor(sum, 32, 64);
      const float sc = __expf(mo - mn);
      scl2[qh] = sc;
      lrun[qh] = lrun[qh] * sc + sum;
      mrun[qh] = mn;
    }

    // ---- P -> wave-private LDS (fp16, swizzled) ----
    #pragma unroll
    for (int qh = 0; qh < 2; ++qh) {
      const int qw = l15 + 16 * qh;
      char* prow = PlB + (wid << 12) + qw * 128;
      #pragma unroll
      for (int mf = 0; mf < 4; ++mf)
        *(f16x4*)(prow + ((32 * mf + 8 * g16) ^ ((qw & 7) << 4))) = pr[mf][qh];
    }

    // ---- rescale yacc ----
    {
      float rs[2][4];
      #pragma unroll
      for (int r = 0; r < 4; ++r) {
        rs[0][r] = __shfl(scl2[0], 4 * g16 + r, 64);
        rs[1][r] = __shfl(scl2[1], 4 * g16 + r, 64);
      }
      #pragma unroll
      for (int qi = 0; qi < 2; ++qi)
        #pragma unroll
        for (int cf = 0; cf < 8; ++cf)
          #pragma unroll
          for (int r = 0; r < 4; ++r)
            yacc[qi][cf][r] *= rs[qi][r];
    }

    __syncthreads();   // #1: g tile arrived; all QK reads of phC done

    if (kt + 1 < kt0 + KTPS)
      stage_phi((kt + 1 - kt0) & 1, kt + 1);   // async; overlaps PV

    // ---- PV: y[q][c] += P[q][m] * g[m][c] ----
    #pragma unroll
    for (int ms = 0; ms < 2; ++ms) {
      const int mb = ms * 64 + g16 * 16;
      const int q0w = l15, q1w = l15 + 16;
      f16x8 pa0 = *(const f16x8*)(PlB + (wid << 12) + q0w * 128 + (mb ^ ((q0w & 7) << 4)));
      f16x8 pa1 = *(const f16x8*)(PlB + (wid << 12) + q1w * 128 + (mb ^ ((q1w & 7) << 4)));
      #pragma unroll
      for (int cf = 0; cf < 8; ++cf) {
        const int c = 16 * cf + l15;
        f16x8 gb = *(const f16x8*)(GlB + c * 128 + (mb ^ ((c & 7) << 4)));
        yacc[0][cf] = __builtin_amdgcn_mfma_f32_16x16x32_f16(pa0, gb, yacc[0][cf], 0, 0, 0);
        yacc[1][cf] = __builtin_amdgcn_mfma_f32_16x16x32_f16(pa1, gb, yacc[1][cf], 0, 0, 0);
      }
    }

    __syncthreads();   // #2: next phi arrived; Gl free for next stage_g
  }

  // ---- epilogue: per-q (m,l); UNNORMALIZED y via LDS transpose ----
  if (g16 == 0) {
    #pragma unroll
    for (int qh = 0; qh < 2; ++qh)
      ml[(size_t)(split * BB + b) * NPIX + n0 + wq0 + 16 * qh + l15] =
          make_float2(mrun[qh], lrun[qh]);
  }
  _Float16* Yl = (_Float16*)smem;   // [128][136]
  #pragma unroll
  for (int qi = 0; qi < 2; ++qi)
    #pragma unroll
    for (int cf = 0; cf < 8; ++cf)
      #pragma unroll
      for (int r = 0; r < 4; ++r)
        Yl[(wq0 + 16 * qi + 4 * g16 + r) * 136 + 16 * cf + l15] =
            (_Float16)yacc[qi][cf][r];
  __syncthreads();
  #pragma unroll
  for (int i = 0; i < 8; ++i) {
    int idx = i * 256 + tid, row = idx >> 4, cg = idx & 15;
    *(int4*)&y_part[(size_t)((split * BB + b) * NPIX + n0 + row) * 128 + cg * 8] =
        *(const int4*)&Yl[row * 136 + cg * 8];
  }
}

// ---------------- K4: W-conv fp16 MFMA + FUSED 3-way split merge ------------
// Per-row merge weights (from ml) are precomputed into LDS; Ys staging reads
// the three unnormalized y_part fragments and combines them on the fly.
// Replaces k_comb entirely (saves its 48 MB of traffic + a launch, at the
// cost of 2 extra y_part reads here).
__global__ __launch_bounds__(256) void k_wconv(
    const _Float16* __restrict__ y_part, const float2* __restrict__ ml,
    const _Float16* __restrict__ Wwh, const float* __restrict__ bw,
    _Float16* __restrict__ z_h)
{
  const int nt = blockIdx.x, ot = blockIdx.y, b = blockIdx.z;
  const int n0 = nt * 128, o0 = ot * 128;
  __shared__ char smem[18432];
  char* WsB = smem;
  char* YsB = smem + 8192;
  float* wrow = (float*)(smem + 16384);   // [128][3] merge weights
  const int tid = threadIdx.x;
  const int l = tid & 63, w = tid >> 6;
  const int l15 = l & 15, g16 = l >> 4;
  const int wo = (w & 1) * 64, wn = (w >> 1) * 64;

  if (tid < 128) {
    int n = n0 + tid;
    float2 a0 = ml[(size_t)b * NPIX + n];
    float2 a1 = ml[(size_t)(BB + b) * NPIX + n];
    float2 a2 = ml[(size_t)(2 * BB + b) * NPIX + n];
    float M = fmaxf(fmaxf(a0.x, a1.x), a2.x);
    float w0 = __expf(a0.x - M), w1 = __expf(a1.x - M), w2 = __expf(a2.x - M);
    float inv = 1.0f / (w0 * a0.y + w1 * a1.y + w2 * a2.y);
    wrow[tid * 3 + 0] = w0 * inv;
    wrow[tid * 3 + 1] = w1 * inv;
    wrow[tid * 3 + 2] = w2 * inv;
  }
  __syncthreads();

  f32x4 acc[4][4] = {};
  for (int k0 = 0; k0 < 128; k0 += 32) {
    #pragma unroll
    for (int i = 0; i < 2; ++i) {
      int idx = i * 256 + tid, r = idx >> 2, cg = idx & 3;
      int sw = (cg ^ ((r >> 1) & 3)) * 16;
      *(int4*)(WsB + r * 64 + sw) =
          *(const int4*)&Wwh[(size_t)(o0 + r) * 128 + k0 + cg * 8];
      const size_t ybase = (size_t)(b * NPIX + n0 + r) * 128 + k0 + cg * 8;
      f16x8 v0 = *(const f16x8*)&y_part[ybase];
      f16x8 v1 = *(const f16x8*)&y_part[ybase + (size_t)BB * NPIX * 128];
      f16x8 v2 = *(const f16x8*)&y_part[ybase + (size_t)2 * BB * NPIX * 128];
      float w0 = wrow[r * 3 + 0], w1 = wrow[r * 3 + 1], w2 = wrow[r * 3 + 2];
      f16x8 o;
      #pragma unroll
      for (int e = 0; e < 8; ++e)
        o[e] = (_Float16)(w0 * (float)v0[e] + w1 * (float)v1[e] + w2 * (float)v2[e]);
      *(f16x8*)(YsB + r * 64 + sw) = o;
    }
    __syncthreads();
    f16x8 af[4], bf[4];
    #pragma unroll
    for (int f = 0; f < 4; ++f) {
      int ro = wo + f * 16 + l15;
      af[f] = *(const f16x8*)(WsB + ro * 64 + ((g16 ^ ((ro >> 1) & 3)) * 16));
      int rn = wn + f * 16 + l15;
      bf[f] = *(const f16x8*)(YsB + rn * 64 + ((g16 ^ ((rn >> 1) & 3)) * 16));
    }
    #pragma unroll
    for (int of = 0; of < 4; ++of)
      #pragma unroll
      for (int pf = 0; pf < 4; ++pf)
        acc[of][pf] = __builtin_amdgcn_mfma_f32_16x16x32_f16(af[of], bf[pf], acc[of][pf], 0, 0, 0);
    __syncthreads();
  }
  #pragma unroll
  for (int of = 0; of < 4; ++of) {
    const float4 bb = *(const float4*)&bw[o0 + wo + of * 16 + g16 * 4];
    float bv[4] = {bb.x, bb.y, bb.z, bb.w};
    #pragma unroll
    for (int pf = 0; pf < 4; ++pf)
      #pragma unroll
      for (int r = 0; r < 4; ++r)
        z_h[(size_t)(b * CC + o0 + wo + of * 16 + g16 * 4 + r) * NPIX +
            n0 + wn + pf * 16 + l15] = (_Float16)(acc[of][pf][r] + bv[r]);
  }
}

// ---------------- K4b: per-channel batch stats (z fp16) ---------------------
__global__ __launch_bounds__(256) void k_stats(
    const _Float16* __restrict__ z_h, float* __restrict__ stats)
{
  const int o = blockIdx.x, t = threadIdx.x;
  float s = 0.f, s2 = 0.f;
  for (int b = 0; b < BB; ++b) {
    const _Float16* z = &z_h[(size_t)(b * CC + o) * NPIX];
    for (int i = t; i < NPIX / 8; i += 256) {
      f16x8 v = *(const f16x8*)&z[i * 8];
      #pragma unroll
      for (int r = 0; r < 8; ++r) {
        float f = (float)v[r];
        s += f; s2 += f * f;
      }
    }
  }
  #pragma unroll
  for (int off = 1; off < 64; off <<= 1) {
    s  += __shfl_xor(s,  off, 64);
    s2 += __shfl_xor(s2, off, 64);
  }
  __shared__ float ls[4], ls2[4];
  if ((t & 63) == 0) { ls[t >> 6] = s; ls2[t >> 6] = s2; }
  __syncthreads();
  if (t == 0) {
    float S  = ls[0] + ls[1] + ls[2] + ls[3];
    float S2 = ls2[0] + ls2[1] + ls2[2] + ls2[3];
    const float invn = 1.0f / (float)(BB * NPIX);
    float mean = S * invn;
    float var  = S2 * invn - mean * mean;
    stats[o] = mean;
    stats[CC + o] = rsqrtf(var + 1e-5f);
  }
}

// ---------------- K5: BN apply + residual (z fp16, 8 elems/thread) ----------
__global__ __launch_bounds__(256) void k_out(
    const _Float16* __restrict__ z_h, const float* __restrict__ x,
    const float* __restrict__ gamma, const float* __restrict__ beta,
    const float* __restrict__ stats, float* __restrict__ out)
{
  int idx = blockIdx.x * 256 + threadIdx.x;
  const int total8 = BB * CC * NPIX / 8;
  if (idx >= total8) return;
  size_t e = (size_t)idx * 8;
  int p = (int)(e % NPIX);
  int o = (int)((e / NPIX) % CC);
  int b = (int)(e / ((size_t)CC * NPIX));
  float a  = stats[CC + o] * gamma[o];
  float c0 = beta[o] - stats[o] * a;
  f16x8 z = *(const f16x8*)&z_h[(size_t)(b * CC + o) * NPIX + p];
  float4 x0 = *(const float4*)&x[e];
  float4 x1 = *(const float4*)&x[e + 4];
  float4 r0, r1;
  r0.x = (float)z[0] * a + c0 + x0.x;
  r0.y = (float)z[1] * a + c0 + x0.y;
  r0.z = (float)z[2] * a + c0 + x0.z;
  r0.w = (float)z[3] * a + c0 + x0.w;
  r1.x = (float)z[4] * a + c0 + x1.x;
  r1.y = (float)z[5] * a + c0 + x1.y;
  r1.z = (float)z[6] * a + c0 + x1.z;
  r1.w = (float)z[7] * a + c0 + x1.w;
  *(float4*)&out[e] = r0;
  *(float4*)&out[e + 4] = r1;
}

extern "C" void kernel_launch(void* const* d_in, const int* in_sizes, int n_in,
                              void* d_out, int out_size, void* d_ws, size_t ws_size,
                              hipStream_t stream)
{
  const float* x     = (const float*)d_in[0];
  const float* Wg    = (const float*)d_in[1];
  const float* bg    = (const float*)d_in[2];
  const float* Wt    = (const float*)d_in[3];
  const float* bt    = (const float*)d_in[4];
  const float* Wp    = (const float*)d_in[5];
  const float* bp    = (const float*)d_in[6];
  const float* Ww    = (const float*)d_in[7];
  const float* bw    = (const float*)d_in[8];
  const float* gamma = (const float*)d_in[9];
  const float* beta  = (const float*)d_in[10];
  float* out = (float*)d_out;

  // workspace (lifetime-aliased):
  //  region A [0, 37.75MB): xt f16 -> y_part f16 [3][4][9216][128] (28.3MB)
  //  region B [37.75, 56.6MB): gphi f16 -> z_h f16 (wconv output; y_part must
  //                            stay live while wconv reads it, so z moved here)
  //  region C [56.6MB ...): th_h, g_h, phi_h, Wall, Wwh, stats, ml[3][4][9216]
  char* wsb = (char*)d_ws;
  _Float16* xt     = (_Float16*)wsb;
  _Float16* y_part = (_Float16*)wsb;
  char* p2 = wsb + 37748736;
  _Float16* gphi  = (_Float16*)p2;
  _Float16* z_h   = (_Float16*)p2;
  char* p3 = p2 + 18874368;
  _Float16* th_h  = (_Float16*)p3;
  _Float16* g_h   = (_Float16*)(p3 + 9437184);
  _Float16* phi_h = (_Float16*)(p3 + 11796480);
  _Float16* Wall  = (_Float16*)(p3 + 14155776);
  _Float16* Wwh   = (_Float16*)(p3 + 14352384);
  float*    stats = (float*)(p3 + 14417920);            // [2][256]
  float2*   ml    = (float2*)(p3 + 14420992);           // [3][4][9216]

  k_prep<<<512, 256, 0, stream>>>(Wt, Wg, Wp, Ww, Wall, Wwh);

  dim3 gxt(NPIX / 64, CC / 64, BB);
  k_xt<<<gxt, 256, 0, stream>>>(x, xt);

  dim3 g1(NPIX / 128, 3, BB);
  k_convA<<<g1, 256, 0, stream>>>(xt, Wall, bt, bg, bp, th_h, gphi);

  dim3 g2(MPIX / 64, 4, BB);
  k_pool2<<<g2, 256, 0, stream>>>(gphi, g_h, phi_h);

  dim3 g3(NPIX / 128, BB, NSPLIT);
  k_attn<<<g3, 256, 0, stream>>>(th_h, phi_h, g_h, y_part, ml);

  dim3 g4(NPIX / 128, CC / 128, BB);
  k_wconv<<<g4, 256, 0, stream>>>(y_part, ml, Wwh, bw, z_h);

  k_stats<<<CC, 256, 0, stream>>>(z_h, stats);

  k_out<<<(BB * CC * NPIX / 8 + 255) / 256, 256, 0, stream>>>(z_h, x, gamma, beta, stats, out);
}